// Round 12
// baseline (184.115 us; speedup 1.0000x reference)
//
#include <hip/hip_runtime.h>
#include <hip/hip_bf16.h>
#include <stdint.h>

#define NROWS 8192
#define NDIM  512
#define MARGIN 0.3f
#define NT    2080     // 64*65/2 upper-triangular 128x128 blocks

typedef __attribute__((ext_vector_type(4))) float floatx4;
typedef __attribute__((ext_vector_type(2))) long longx2;

// pack 4 floats -> 4 OCP e4m3 bytes (HW cvt, RNE, saturating)
__device__ inline unsigned cvt4_fp8(float4 f) {
  int v = 0;
  v = __builtin_amdgcn_cvt_pk_fp8_f32(f.x, f.y, v, false);
  v = __builtin_amdgcn_cvt_pk_fp8_f32(f.z, f.w, v, true);
  return (unsigned)v;
}

// fp32 -> fp8 e4m3, 16 floats/thread; zeroes the (poisoned) output scalar
__global__ void convert_kernel(const float4* __restrict__ in, uint4* __restrict__ out,
                               float* __restrict__ loss_out) {
  int i = blockIdx.x * blockDim.x + threadIdx.x;
  if (i == 0) loss_out[0] = 0.f;
  float4 f0 = in[i * 4 + 0], f1 = in[i * 4 + 1], f2 = in[i * 4 + 2], f3 = in[i * 4 + 3];
  uint4 o;
  o.x = cvt4_fp8(f0);
  o.y = cvt4_fp8(f1);
  o.z = cvt4_fp8(f2);
  o.w = cvt4_fp8(f3);
  out[i] = o;
}

__device__ inline void gload_lds16(const void* g, void* l) {
  __builtin_amdgcn_global_load_lds(
      (const __attribute__((address_space(1))) unsigned int*)g,
      (__attribute__((address_space(3))) unsigned int*)l, 16, 0, 0);
}

// sigma: swap bits 0 and 1 (self-inverse). LDS slot s holds global row sigma(s);
// fragment row r lives at slot sigma(r). ds_read_b128 base-bank becomes
// 16*bit1(row) + 4*quad -> b128 reads run at the m134 throughput floor
// (R9-verified), while lane->k mapping stays row-independent (MFMA K-safe).
__device__ inline int sigma2(int r) {
  return (r & ~3) | ((r & 1) << 1) | ((r >> 1) & 1);
}

// 128x128 upper-tri blocks of sim = X·X^T, fp8 e4m3 non-scaled MFMA (= bf16
// rate, half of bf16's bytes). 4 waves (2x2 of 64x64), BK=64, 2-stage LDS
// pipeline (exactly 32 KB), raw s_barrier, per-wave vmcnt(0) on loads issued
// one full compute-phase earlier. launch_bounds(256,3): cap 170 regs — the
// 64-AGPR accumulator + ~80 arch regs fit WITHOUT spill (R11's (256,4)
// spilled 20 MB to scratch and gave back the occupancy win).
__launch_bounds__(256, 3)
__global__ void loss_kernel(const unsigned char* __restrict__ Xb, const int* __restrict__ tg,
                            float* __restrict__ out) {
  __shared__ __align__(16) unsigned char As[2][8192];   // 128 slots x 64 B
  __shared__ __align__(16) unsigned char Bs[2][8192];   // total 32768 B

  // super-tile decode (8 diagonal supers of 36, then 28 off-diag of 64)
  int t = blockIdx.x;
  int bi, bj;
  if (t < 288) {
    int si = t / 36;
    int q  = t - si * 36;
    int ii = 0;
    while (q >= 8 - ii) { q -= 8 - ii; ii++; }
    bi = si * 8 + ii;
    bj = si * 8 + ii + q;
  } else {
    int q = t - 288;
    int s = q >> 6, r = q & 63;
    int si = 0;
    while (s >= 7 - si) { s -= 7 - si; si++; }
    int sj = si + 1 + s;
    bi = si * 8 + (r >> 3);
    bj = sj * 8 + (r & 7);
  }

  const int tid  = threadIdx.x;
  const int lane = tid & 63;
  const int w    = tid >> 6;
  const int wm   = w >> 1, wn = w & 1;   // 2x2 waves, 64x64 each
  const int quad = lane >> 4;
  const int l16  = lane & 15;

  const int rowBase = bi * 128;
  const int colBase = bj * 128;

  // staging: tile = 128 slots x 64 B = 8 chunks of 1 KB (16 slots each);
  // wave w stages chunks {2w, 2w+1} of A and of B (4 DMA loads/wave/stage).
  // Chunk lane d deposits 16 B at slot ch*16 + (d>>2), unit (d&3); it fetches
  // global row sigma(slot), same k-unit.
  const int slot = lane >> 2;
  const int unit = lane & 3;
  unsigned gA[2], gB[2];
#pragma unroll
  for (int c = 0; c < 2; c++) {
    int ch = w * 2 + c;
    int gr = sigma2(ch * 16 + slot);
    gA[c] = (unsigned)((rowBase + gr) * NDIM + unit * 16);
    gB[c] = (unsigned)((colBase + gr) * NDIM + unit * 16);
  }

#define STAGE(KT, BUF)                                                    \
  do {                                                                    \
    _Pragma("unroll")                                                     \
    for (int c = 0; c < 2; c++) {                                         \
      int ch = w * 2 + c;                                                 \
      gload_lds16(Xb + gA[c] + (KT) * 64, &As[BUF][ch * 1024]);           \
      gload_lds16(Xb + gB[c] + (KT) * 64, &Bs[BUF][ch * 1024]);           \
    }                                                                     \
  } while (0)

  floatx4 acc[4][4];
#pragma unroll
  for (int a = 0; a < 4; a++)
#pragma unroll
    for (int b = 0; b < 4; b++) acc[a][b] = (floatx4)(0.f);

  STAGE(0, 0);

#pragma unroll
  for (int kt = 0; kt < 8; kt++) {
    const int buf = kt & 1;
    // own stage-kt DMA drained (issued one compute-phase ago -> cheap);
    // barrier => ALL waves' stage-kt chunks landed AND all kt-1 reads done.
    asm volatile("s_waitcnt vmcnt(0)" ::: "memory");
    asm volatile("s_barrier" ::: "memory");          // raw: no lgkm drain
    if (kt < 7) STAGE(kt + 1, buf ^ 1);              // flies under kt compute

    // one b128 per fragment = two mfma k-steps (K-permutation invariant)
    longx2 a[4], b[4];
#pragma unroll
    for (int mt = 0; mt < 4; mt++) {
      const int row = wm * 64 + mt * 16 + l16;
      a[mt] = *(const longx2*)(&As[buf][sigma2(row) * 64 + quad * 16]);
    }
#pragma unroll
    for (int nt = 0; nt < 4; nt++) {
      const int row = wn * 64 + nt * 16 + l16;
      b[nt] = *(const longx2*)(&Bs[buf][sigma2(row) * 64 + quad * 16]);
    }
#pragma unroll
    for (int mt = 0; mt < 4; mt++)
#pragma unroll
      for (int nt = 0; nt < 4; nt++) {
        acc[mt][nt] = __builtin_amdgcn_mfma_f32_16x16x32_fp8_fp8(a[mt][0], b[nt][0],
                                                                 acc[mt][nt], 0, 0, 0);
        acc[mt][nt] = __builtin_amdgcn_mfma_f32_16x16x32_fp8_fp8(a[mt][1], b[nt][1],
                                                                 acc[mt][nt], 0, 0, 0);
      }
  }

  // Epilogue. C/D layout: col = lane&15, row = quad*4 + reg.
  // Labels loaded HERE (epilogue-local liveness keeps the K-loop lean).
  float lsum = 0.f;
  const bool diag = (bi == bj);
  int tc[4];
#pragma unroll
  for (int nt = 0; nt < 4; nt++)
    tc[nt] = tg[colBase + wn * 64 + nt * 16 + l16];

  if (!diag) {
    // uniform pair-weight 2 hoisted to the final atomic
#pragma unroll
    for (int mt = 0; mt < 4; mt++) {
      const int4 rlv = *(const int4*)(tg + rowBase + wm * 64 + mt * 16 + quad * 4);
      const int rlab[4] = {rlv.x, rlv.y, rlv.z, rlv.w};
#pragma unroll
      for (int nt = 0; nt < 4; nt++) {
#pragma unroll
        for (int r = 0; r < 4; r++) {
          const float s = acc[mt][nt][r];
          lsum += (rlab[r] == tc[nt]) ? ((s < 1.f) ? 1.f - s : 0.f)
                                      : ((s > MARGIN) ? s : 0.f);
        }
      }
    }
    lsum *= 2.f;
  } else {
#pragma unroll
    for (int mt = 0; mt < 4; mt++) {
      const int rloc = wm * 64 + mt * 16 + quad * 4;
      const int4 rlv = *(const int4*)(tg + rowBase + rloc);
      const int rlab[4] = {rlv.x, rlv.y, rlv.z, rlv.w};
#pragma unroll
      for (int nt = 0; nt < 4; nt++) {
        const int col = colBase + wn * 64 + nt * 16 + l16;
#pragma unroll
        for (int r = 0; r < 4; r++) {
          const float s = acc[mt][nt][r];
          float c = (rlab[r] == tc[nt]) ? ((s < 1.f) ? 1.f - s : 0.f)
                                        : ((s > MARGIN) ? s : 0.f);
          const int row = rowBase + rloc + r;
          float wgt = (row < col) ? 2.f : ((row == col) ? 1.f : 0.f);
          lsum += wgt * c;
        }
      }
    }
  }

  // wave-level reduce, one device-scope atomic per wave (no LDS, no barrier)
#pragma unroll
  for (int off = 32; off > 0; off >>= 1) lsum += __shfl_down(lsum, off, 64);
  if (lane == 0) atomicAdd(out, lsum * (1.0f / NROWS));
}

extern "C" void kernel_launch(void* const* d_in, const int* in_sizes, int n_in,
                              void* d_out, int out_size, void* d_ws, size_t ws_size,
                              hipStream_t stream) {
  const float* x = (const float*)d_in[0];
  const int* tg  = (const int*)d_in[1];
  float* out     = (float*)d_out;
  unsigned char* xb = (unsigned char*)d_ws;   // fp8 X, 4 MiB

  convert_kernel<<<(NROWS * NDIM / 16) / 256, 256, 0, stream>>>(
      (const float4*)x, (uint4*)xb, out);
  loss_kernel<<<NT, 256, 0, stream>>>(xb, tg, out);
}

// Round 13
// 104.683 us; speedup vs baseline: 1.7588x; 1.7588x over previous
//
#include <hip/hip_runtime.h>
#include <hip/hip_bf16.h>
#include <stdint.h>

#define NROWS 8192
#define NDIM  512
#define MARGIN 0.3f
#define NT    2080     // 64*65/2 upper-triangular 128x128 blocks

typedef __attribute__((ext_vector_type(4))) float floatx4;
typedef __attribute__((ext_vector_type(2))) long longx2;

// pack 4 floats -> 4 OCP e4m3 bytes (HW cvt, RNE, saturating)
__device__ inline unsigned cvt4_fp8(float4 f) {
  int v = 0;
  v = __builtin_amdgcn_cvt_pk_fp8_f32(f.x, f.y, v, false);
  v = __builtin_amdgcn_cvt_pk_fp8_f32(f.z, f.w, v, true);
  return (unsigned)v;
}

// fp32 -> fp8 e4m3, 16 floats/thread
__global__ void convert_kernel(const float4* __restrict__ in, uint4* __restrict__ out) {
  int i = blockIdx.x * blockDim.x + threadIdx.x;
  float4 f0 = in[i * 4 + 0], f1 = in[i * 4 + 1], f2 = in[i * 4 + 2], f3 = in[i * 4 + 3];
  uint4 o;
  o.x = cvt4_fp8(f0);
  o.y = cvt4_fp8(f1);
  o.z = cvt4_fp8(f2);
  o.w = cvt4_fp8(f3);
  out[i] = o;
}

__device__ inline void gload_lds16(const void* g, void* l) {
  __builtin_amdgcn_global_load_lds(
      (const __attribute__((address_space(1))) unsigned int*)g,
      (__attribute__((address_space(3))) unsigned int*)l, 16, 0, 0);
}

// sigma: swap bits 0 and 1 (self-inverse). LDS slot s holds global row sigma(s);
// fragment row r lives at slot sigma(r). Keeps ds_read_b128 at the m134
// throughput floor (R9-verified) with a row-independent lane->k map.
__device__ inline int sigma2(int r) {
  return (r & ~3) | ((r & 1) << 1) | ((r >> 1) & 1);
}

// 128x128 upper-tri blocks of sim = X·X^T, fp8 e4m3 non-scaled MFMA (= bf16
// rate, half of bf16's bytes). 4 waves (2x2 of 64x64), BK=64, 2-stage LDS
// pipeline (32 KB), raw s_barrier, per-wave vmcnt(0) on loads issued one full
// compute-phase earlier. launch_bounds(256,3): no spill (R11's (256,4)
// spilled 20 MB). NO atomics: block partial -> d_ws (R10/R12's 8320
// same-address atomics serialized at ~14.7 ns each = the 122 us wall).
__launch_bounds__(256, 3)
__global__ void loss_kernel(const unsigned char* __restrict__ Xb, const int* __restrict__ tg,
                            float* __restrict__ partials) {
  __shared__ __align__(16) unsigned char As[2][8192];   // 128 slots x 64 B
  __shared__ __align__(16) unsigned char Bs[2][8192];
  __shared__ float red[4];

  // super-tile decode (8 diagonal supers of 36, then 28 off-diag of 64)
  int t = blockIdx.x;
  int bi, bj;
  if (t < 288) {
    int si = t / 36;
    int q  = t - si * 36;
    int ii = 0;
    while (q >= 8 - ii) { q -= 8 - ii; ii++; }
    bi = si * 8 + ii;
    bj = si * 8 + ii + q;
  } else {
    int q = t - 288;
    int s = q >> 6, r = q & 63;
    int si = 0;
    while (s >= 7 - si) { s -= 7 - si; si++; }
    int sj = si + 1 + s;
    bi = si * 8 + (r >> 3);
    bj = sj * 8 + (r & 7);
  }

  const int tid  = threadIdx.x;
  const int lane = tid & 63;
  const int w    = tid >> 6;
  const int wm   = w >> 1, wn = w & 1;   // 2x2 waves, 64x64 each
  const int quad = lane >> 4;
  const int l16  = lane & 15;

  const int rowBase = bi * 128;
  const int colBase = bj * 128;

  // staging: tile = 128 slots x 64 B = 8 chunks of 1 KB (16 slots each);
  // wave w stages chunks {2w, 2w+1} of A and of B (4 DMA loads/wave/stage).
  // Chunk lane d deposits 16 B at slot ch*16 + (d>>2), unit (d&3); it fetches
  // global row sigma(slot), same k-unit.
  const int slot = lane >> 2;
  const int unit = lane & 3;
  unsigned gA[2], gB[2];
#pragma unroll
  for (int c = 0; c < 2; c++) {
    int ch = w * 2 + c;
    int gr = sigma2(ch * 16 + slot);
    gA[c] = (unsigned)((rowBase + gr) * NDIM + unit * 16);
    gB[c] = (unsigned)((colBase + gr) * NDIM + unit * 16);
  }

#define STAGE(KT, BUF)                                                    \
  do {                                                                    \
    _Pragma("unroll")                                                     \
    for (int c = 0; c < 2; c++) {                                         \
      int ch = w * 2 + c;                                                 \
      gload_lds16(Xb + gA[c] + (KT) * 64, &As[BUF][ch * 1024]);           \
      gload_lds16(Xb + gB[c] + (KT) * 64, &Bs[BUF][ch * 1024]);           \
    }                                                                     \
  } while (0)

  floatx4 acc[4][4];
#pragma unroll
  for (int a = 0; a < 4; a++)
#pragma unroll
    for (int b = 0; b < 4; b++) acc[a][b] = (floatx4)(0.f);

  STAGE(0, 0);

#pragma unroll
  for (int kt = 0; kt < 8; kt++) {
    const int buf = kt & 1;
    // own stage-kt DMA drained (issued one compute-phase ago -> cheap);
    // barrier => ALL waves' stage-kt chunks landed AND all kt-1 reads done.
    asm volatile("s_waitcnt vmcnt(0)" ::: "memory");
    asm volatile("s_barrier" ::: "memory");          // raw: no lgkm drain
    if (kt < 7) STAGE(kt + 1, buf ^ 1);              // flies under kt compute

    // one b128 per fragment = two mfma k-steps (K-permutation invariant)
    longx2 a[4], b[4];
#pragma unroll
    for (int mt = 0; mt < 4; mt++) {
      const int row = wm * 64 + mt * 16 + l16;
      a[mt] = *(const longx2*)(&As[buf][sigma2(row) * 64 + quad * 16]);
    }
#pragma unroll
    for (int nt = 0; nt < 4; nt++) {
      const int row = wn * 64 + nt * 16 + l16;
      b[nt] = *(const longx2*)(&Bs[buf][sigma2(row) * 64 + quad * 16]);
    }
#pragma unroll
    for (int mt = 0; mt < 4; mt++)
#pragma unroll
      for (int nt = 0; nt < 4; nt++) {
        acc[mt][nt] = __builtin_amdgcn_mfma_f32_16x16x32_fp8_fp8(a[mt][0], b[nt][0],
                                                                 acc[mt][nt], 0, 0, 0);
        acc[mt][nt] = __builtin_amdgcn_mfma_f32_16x16x32_fp8_fp8(a[mt][1], b[nt][1],
                                                                 acc[mt][nt], 0, 0, 0);
      }
  }

  // Epilogue. C/D layout: col = lane&15, row = quad*4 + reg.
  float lsum = 0.f;
  const bool diag = (bi == bj);
  int tc[4];
#pragma unroll
  for (int nt = 0; nt < 4; nt++)
    tc[nt] = tg[colBase + wn * 64 + nt * 16 + l16];

  if (!diag) {
#pragma unroll
    for (int mt = 0; mt < 4; mt++) {
      const int4 rlv = *(const int4*)(tg + rowBase + wm * 64 + mt * 16 + quad * 4);
      const int rlab[4] = {rlv.x, rlv.y, rlv.z, rlv.w};
#pragma unroll
      for (int nt = 0; nt < 4; nt++) {
#pragma unroll
        for (int r = 0; r < 4; r++) {
          const float s = acc[mt][nt][r];
          lsum += (rlab[r] == tc[nt]) ? ((s < 1.f) ? 1.f - s : 0.f)
                                      : ((s > MARGIN) ? s : 0.f);
        }
      }
    }
    lsum *= 2.f;     // pair weight hoisted
  } else {
#pragma unroll
    for (int mt = 0; mt < 4; mt++) {
      const int rloc = wm * 64 + mt * 16 + quad * 4;
      const int4 rlv = *(const int4*)(tg + rowBase + rloc);
      const int rlab[4] = {rlv.x, rlv.y, rlv.z, rlv.w};
#pragma unroll
      for (int nt = 0; nt < 4; nt++) {
        const int col = colBase + wn * 64 + nt * 16 + l16;
#pragma unroll
        for (int r = 0; r < 4; r++) {
          const float s = acc[mt][nt][r];
          float c = (rlab[r] == tc[nt]) ? ((s < 1.f) ? 1.f - s : 0.f)
                                        : ((s > MARGIN) ? s : 0.f);
          const int row = rowBase + rloc + r;
          float wgt = (row < col) ? 2.f : ((row == col) ? 1.f : 0.f);
          lsum += wgt * c;
        }
      }
    }
  }

  // block reduce, then ONE non-atomic partial store per block
#pragma unroll
  for (int off = 32; off > 0; off >>= 1) lsum += __shfl_down(lsum, off, 64);
  if (lane == 0) red[w] = lsum;
  __syncthreads();
  if (tid == 0) partials[blockIdx.x] = red[0] + red[1] + red[2] + red[3];
}

// 2080 partials -> scalar; one 256-thread block, ~2 us
__global__ void reduce_kernel(const float* __restrict__ partials, float* __restrict__ out) {
  __shared__ float red[4];
  float s = 0.f;
  for (int i = threadIdx.x; i < NT; i += 256) s += partials[i];
#pragma unroll
  for (int off = 32; off > 0; off >>= 1) s += __shfl_down(s, off, 64);
  if ((threadIdx.x & 63) == 0) red[threadIdx.x >> 6] = s;
  __syncthreads();
  if (threadIdx.x == 0)
    out[0] = (red[0] + red[1] + red[2] + red[3]) * (1.0f / NROWS);
}

extern "C" void kernel_launch(void* const* d_in, const int* in_sizes, int n_in,
                              void* d_out, int out_size, void* d_ws, size_t ws_size,
                              hipStream_t stream) {
  const float* x = (const float*)d_in[0];
  const int* tg  = (const int*)d_in[1];
  float* out     = (float*)d_out;
  unsigned char* xb = (unsigned char*)d_ws;                    // fp8 X, 4 MiB
  float* partials   = (float*)((char*)d_ws + (4u << 20));      // 2080 floats

  convert_kernel<<<(NROWS * NDIM / 16) / 256, 256, 0, stream>>>(
      (const float4*)x, (uint4*)xb);
  loss_kernel<<<NT, 256, 0, stream>>>(xb, tg, partials);
  reduce_kernel<<<1, 256, 0, stream>>>(partials, out);
}

// Round 14
// 100.902 us; speedup vs baseline: 1.8247x; 1.0375x over previous
//
#include <hip/hip_runtime.h>
#include <hip/hip_bf16.h>
#include <stdint.h>

#define NROWS 8192
#define NDIM  512
#define MARGIN 0.3f
#define NT    2080     // 64*65/2 upper-triangular 128x128 blocks

typedef __attribute__((ext_vector_type(16))) float floatx16;
typedef __attribute__((ext_vector_type(8)))  int   intx8;

// pack 4 floats -> 4 OCP e4m3 bytes (HW cvt, RNE, saturating)
__device__ inline unsigned cvt4_fp8(float4 f) {
  int v = 0;
  v = __builtin_amdgcn_cvt_pk_fp8_f32(f.x, f.y, v, false);
  v = __builtin_amdgcn_cvt_pk_fp8_f32(f.z, f.w, v, true);
  return (unsigned)v;
}

// fp32 -> fp8 e4m3, 16 floats/thread
__global__ void convert_kernel(const float4* __restrict__ in, uint4* __restrict__ out) {
  int i = blockIdx.x * blockDim.x + threadIdx.x;
  float4 f0 = in[i * 4 + 0], f1 = in[i * 4 + 1], f2 = in[i * 4 + 2], f3 = in[i * 4 + 3];
  uint4 o;
  o.x = cvt4_fp8(f0);
  o.y = cvt4_fp8(f1);
  o.z = cvt4_fp8(f2);
  o.w = cvt4_fp8(f3);
  out[i] = o;
}

__device__ inline void gload_lds16(const void* g, void* l) {
  __builtin_amdgcn_global_load_lds(
      (const __attribute__((address_space(1))) unsigned int*)g,
      (__attribute__((address_space(3))) unsigned int*)l, 16, 0, 0);
}

// 128x128 upper-tri blocks of sim = X·X^T, fp8 e4m3 via MX-scaled
// v_mfma_scale_f32_32x32x64_f8f6f4 (scale = 1.0) -> 2x non-scaled fp8 rate,
// 8x fewer MFMA issue slots (128/block). R10 proved this core numerically
// correct; its 122 us was the per-wave atomic funnel (fixed in R13).
// Skeleton = R13: 4 waves (2x2 of 64x64, each 2x2 of 32x32), BK=64, 2-stage
// 32 KB LDS, per-wave vmcnt(0) + raw s_barrier, stage-after-barrier,
// block partial -> d_ws, separate reduce kernel. launch_bounds(256,3): no
// spill (R11's (256,4) spilled).
// Swizzle: u_phys = u_log ^ ((row>>2)&3). Bank math for the 32-row fragment
// reads: 8 lanes per 4-bank span = conflict-free on both b128s.
__launch_bounds__(256, 3)
__global__ void loss_kernel(const unsigned char* __restrict__ Xb, const int* __restrict__ tg,
                            float* __restrict__ partials) {
  __shared__ __align__(16) unsigned char As[2][8192];   // 128 rows x 64 B
  __shared__ __align__(16) unsigned char Bs[2][8192];
  __shared__ float red[4];

  // super-tile decode (8 diagonal supers of 36, then 28 off-diag of 64)
  int t = blockIdx.x;
  int bi, bj;
  if (t < 288) {
    int si = t / 36;
    int q  = t - si * 36;
    int ii = 0;
    while (q >= 8 - ii) { q -= 8 - ii; ii++; }
    bi = si * 8 + ii;
    bj = si * 8 + ii + q;
  } else {
    int q = t - 288;
    int s = q >> 6, r = q & 63;
    int si = 0;
    while (s >= 7 - si) { s -= 7 - si; si++; }
    int sj = si + 1 + s;
    bi = si * 8 + (r >> 3);
    bj = sj * 8 + (r & 7);
  }

  const int tid  = threadIdx.x;
  const int lane = tid & 63;
  const int w    = tid >> 6;
  const int wm   = w >> 1, wn = w & 1;   // 2x2 waves, 64x64 each
  const int g    = lane >> 5;            // MFMA k-group (0/1)
  const int m32  = lane & 31;            // MFMA row/col within 32

  const int rowBase = bi * 128;
  const int colBase = bj * 128;

  // staging: tile = 128 rows x 64 B = 8 chunks of 1 KB (16 rows each);
  // wave w stages chunks {2w, 2w+1} of A and of B (4 DMA loads/wave/stage).
  // Chunk lane d: row = ch*16 + (d>>2), u_phys = d&3; fetches global k-unit
  // u_log = u_phys ^ ((row>>2)&3).
  const int srow = lane >> 2;
  const int sup  = lane & 3;
  unsigned gA[2], gB[2];
#pragma unroll
  for (int c = 0; c < 2; c++) {
    int ch  = w * 2 + c;
    int row = ch * 16 + srow;
    int ul  = sup ^ ((row >> 2) & 3);
    gA[c] = (unsigned)((rowBase + row) * NDIM + ul * 16);
    gB[c] = (unsigned)((colBase + row) * NDIM + ul * 16);
  }

#define STAGE(KT, BUF)                                                    \
  do {                                                                    \
    _Pragma("unroll")                                                     \
    for (int c = 0; c < 2; c++) {                                         \
      int ch = w * 2 + c;                                                 \
      gload_lds16(Xb + gA[c] + (KT) * 64, &As[BUF][ch * 1024]);           \
      gload_lds16(Xb + gB[c] + (KT) * 64, &Bs[BUF][ch * 1024]);           \
    }                                                                     \
  } while (0)

  floatx16 acc[2][2];
#pragma unroll
  for (int a = 0; a < 2; a++)
#pragma unroll
    for (int b = 0; b < 2; b++) acc[a][b] = (floatx16)(0.f);

  STAGE(0, 0);

#pragma unroll
  for (int kt = 0; kt < 8; kt++) {
    const int buf = kt & 1;
    // own stage-kt DMA drained (issued one compute-phase ago -> cheap);
    // barrier => ALL waves' stage-kt chunks landed AND all kt-1 reads done.
    asm volatile("s_waitcnt vmcnt(0)" ::: "memory");
    asm volatile("s_barrier" ::: "memory");          // raw: no lgkm drain
    if (kt < 7) STAGE(kt + 1, buf ^ 1);              // flies under kt compute

    // fragments: lane holds k = g*32 + [0,32) of its row as 2 x b128
    // (u_log = 2g, 2g+1), un-swizzled via u_phys = u_log ^ ((row>>2)&3)
    intx8 af[2], bf[2];
#pragma unroll
    for (int mt = 0; mt < 2; mt++) {
      const int row = wm * 64 + mt * 32 + m32;
      const int x = (row >> 2) & 3;
      int4 lo = *(const int4*)(&As[buf][row * 64 + ((2 * g)     ^ x) * 16]);
      int4 hi = *(const int4*)(&As[buf][row * 64 + ((2 * g + 1) ^ x) * 16]);
      intx8 f; f[0]=lo.x; f[1]=lo.y; f[2]=lo.z; f[3]=lo.w;
               f[4]=hi.x; f[5]=hi.y; f[6]=hi.z; f[7]=hi.w;
      af[mt] = f;
    }
#pragma unroll
    for (int nt = 0; nt < 2; nt++) {
      const int row = wn * 64 + nt * 32 + m32;
      const int x = (row >> 2) & 3;
      int4 lo = *(const int4*)(&Bs[buf][row * 64 + ((2 * g)     ^ x) * 16]);
      int4 hi = *(const int4*)(&Bs[buf][row * 64 + ((2 * g + 1) ^ x) * 16]);
      intx8 f; f[0]=lo.x; f[1]=lo.y; f[2]=lo.z; f[3]=lo.w;
               f[4]=hi.x; f[5]=hi.y; f[6]=hi.z; f[7]=hi.w;
      bf[nt] = f;
    }
#pragma unroll
    for (int mt = 0; mt < 2; mt++)
#pragma unroll
      for (int nt = 0; nt < 2; nt++)
        acc[mt][nt] = __builtin_amdgcn_mfma_scale_f32_32x32x64_f8f6f4(
            af[mt], bf[nt], acc[mt][nt],
            0 /*A fmt: fp8 e4m3*/, 0 /*B fmt: fp8 e4m3*/,
            0, 127 /*scaleA = 2^0*/, 0, 127 /*scaleB = 2^0*/);
  }

  // Epilogue (R10-verified). 32x32 C/D layout [m74/m101]: col = lane&31,
  // row = (reg&3) + 8*(reg>>2) + 4*(lane>>5), reg in [0,16).
  float lsum = 0.f;
  const bool diag = (bi == bj);
  if (!diag) {
#pragma unroll
    for (int mt = 0; mt < 2; mt++) {
#pragma unroll
      for (int nt = 0; nt < 2; nt++) {
        const int tc = tg[colBase + wn * 64 + nt * 32 + m32];
#pragma unroll
        for (int q = 0; q < 4; q++) {
          const int4 rlv = *(const int4*)(tg + rowBase + wm * 64 + mt * 32 + 4 * g + 8 * q);
          const int rlab[4] = {rlv.x, rlv.y, rlv.z, rlv.w};
#pragma unroll
          for (int j = 0; j < 4; j++) {
            const float s = acc[mt][nt][q * 4 + j];
            lsum += (rlab[j] == tc) ? ((s < 1.f) ? 1.f - s : 0.f)
                                    : ((s > MARGIN) ? s : 0.f);
          }
        }
      }
    }
    lsum *= 2.f;     // pair weight hoisted
  } else {
#pragma unroll
    for (int mt = 0; mt < 2; mt++) {
#pragma unroll
      for (int nt = 0; nt < 2; nt++) {
        const int cloc = wn * 64 + nt * 32 + m32;
        const int tc = tg[colBase + cloc];
        const int col = colBase + cloc;
#pragma unroll
        for (int q = 0; q < 4; q++) {
          const int rbase = wm * 64 + mt * 32 + 4 * g + 8 * q;
          const int4 rlv = *(const int4*)(tg + rowBase + rbase);
          const int rlab[4] = {rlv.x, rlv.y, rlv.z, rlv.w};
#pragma unroll
          for (int j = 0; j < 4; j++) {
            const float s = acc[mt][nt][q * 4 + j];
            float c = (rlab[j] == tc) ? ((s < 1.f) ? 1.f - s : 0.f)
                                      : ((s > MARGIN) ? s : 0.f);
            const int row = rowBase + rbase + j;
            float wgt = (row < col) ? 2.f : ((row == col) ? 1.f : 0.f);
            lsum += wgt * c;
          }
        }
      }
    }
  }

  // block reduce, ONE non-atomic partial store per block
#pragma unroll
  for (int off = 32; off > 0; off >>= 1) lsum += __shfl_down(lsum, off, 64);
  if (lane == 0) red[w] = lsum;
  __syncthreads();
  if (tid == 0) partials[blockIdx.x] = red[0] + red[1] + red[2] + red[3];
}

// 2080 partials -> scalar; one 256-thread block
__global__ void reduce_kernel(const float* __restrict__ partials, float* __restrict__ out) {
  __shared__ float red[4];
  float s = 0.f;
  for (int i = threadIdx.x; i < NT; i += 256) s += partials[i];
#pragma unroll
  for (int off = 32; off > 0; off >>= 1) s += __shfl_down(s, off, 64);
  if ((threadIdx.x & 63) == 0) red[threadIdx.x >> 6] = s;
  __syncthreads();
  if (threadIdx.x == 0)
    out[0] = (red[0] + red[1] + red[2] + red[3]) * (1.0f / NROWS);
}

extern "C" void kernel_launch(void* const* d_in, const int* in_sizes, int n_in,
                              void* d_out, int out_size, void* d_ws, size_t ws_size,
                              hipStream_t stream) {
  const float* x = (const float*)d_in[0];
  const int* tg  = (const int*)d_in[1];
  float* out     = (float*)d_out;
  unsigned char* xb = (unsigned char*)d_ws;                    // fp8 X, 4 MiB
  float* partials   = (float*)((char*)d_ws + (4u << 20));      // 2080 floats

  convert_kernel<<<(NROWS * NDIM / 16) / 256, 256, 0, stream>>>(
      (const float4*)x, (uint4*)xb);
  loss_kernel<<<NT, 256, 0, stream>>>(xb, tg, partials);
  reduce_kernel<<<1, 256, 0, stream>>>(partials, out);
}

// Round 15
// 99.425 us; speedup vs baseline: 1.8518x; 1.0149x over previous
//
#include <hip/hip_runtime.h>
#include <hip/hip_bf16.h>
#include <stdint.h>

#define NROWS 8192
#define NDIM  512
#define MARGIN 0.3f
#define NT    2080     // 64*65/2 upper-triangular 128x128 blocks

typedef __attribute__((ext_vector_type(16))) float floatx16;
typedef __attribute__((ext_vector_type(8)))  int   intx8;

// pack 4 floats -> 4 OCP e4m3 bytes (HW cvt, RNE, saturating)
__device__ inline unsigned cvt4_fp8(float4 f) {
  int v = 0;
  v = __builtin_amdgcn_cvt_pk_fp8_f32(f.x, f.y, v, false);
  v = __builtin_amdgcn_cvt_pk_fp8_f32(f.z, f.w, v, true);
  return (unsigned)v;
}

// fp32 -> fp8 e4m3, 16 floats/thread
__global__ void convert_kernel(const float4* __restrict__ in, uint4* __restrict__ out) {
  int i = blockIdx.x * blockDim.x + threadIdx.x;
  float4 f0 = in[i * 4 + 0], f1 = in[i * 4 + 1], f2 = in[i * 4 + 2], f3 = in[i * 4 + 3];
  uint4 o;
  o.x = cvt4_fp8(f0);
  o.y = cvt4_fp8(f1);
  o.z = cvt4_fp8(f2);
  o.w = cvt4_fp8(f3);
  out[i] = o;
}

__device__ inline void gload_lds16(const void* g, void* l) {
  __builtin_amdgcn_global_load_lds(
      (const __attribute__((address_space(1))) unsigned int*)g,
      (__attribute__((address_space(3))) unsigned int*)l, 16, 0, 0);
}

// 128x128 upper-tri blocks of sim = X·X^T, fp8 e4m3 via MX-scaled
// v_mfma_scale_f32_32x32x64_f8f6f4 (scale = 1.0; 2x non-scaled fp8 rate,
// R10/R14-verified correct). R15 = R14 core on R9's deeper pipeline:
// 3-stage BK=64 LDS (48 KB -> 3 blocks/CU, same occupancy as R14's 32 KB
// since regs cap at 3), prefetch distance TWO iterations (~1400 cyc >> L2/L3
// DMA latency — R14's distance-1 stopped covering it once scaled MFMA
// shortened the compute phase), per-wave `s_waitcnt vmcnt(4)` mid-loop
// (tile kt landed, kt+1's 4 loads stay in flight; never vmcnt(0) until the
// last iter), raw s_barrier (no lgkm drain), stage-after-barrier (WAR on the
// 3rd buffer is barrier-ordered). Block partial -> d_ws; separate reduce.
__launch_bounds__(256, 3)
__global__ void loss_kernel(const unsigned char* __restrict__ Xb, const int* __restrict__ tg,
                            float* __restrict__ partials) {
  __shared__ __align__(16) unsigned char As[3][8192];   // 128 rows x 64 B
  __shared__ __align__(16) unsigned char Bs[3][8192];
  __shared__ float red[4];

  // super-tile decode (8 diagonal supers of 36, then 28 off-diag of 64)
  int t = blockIdx.x;
  int bi, bj;
  if (t < 288) {
    int si = t / 36;
    int q  = t - si * 36;
    int ii = 0;
    while (q >= 8 - ii) { q -= 8 - ii; ii++; }
    bi = si * 8 + ii;
    bj = si * 8 + ii + q;
  } else {
    int q = t - 288;
    int s = q >> 6, r = q & 63;
    int si = 0;
    while (s >= 7 - si) { s -= 7 - si; si++; }
    int sj = si + 1 + s;
    bi = si * 8 + (r >> 3);
    bj = sj * 8 + (r & 7);
  }

  const int tid  = threadIdx.x;
  const int lane = tid & 63;
  const int w    = tid >> 6;
  const int wm   = w >> 1, wn = w & 1;   // 2x2 waves, 64x64 each
  const int g    = lane >> 5;            // MFMA k-group (0/1)
  const int m32  = lane & 31;            // MFMA row/col within 32

  const int rowBase = bi * 128;
  const int colBase = bj * 128;

  // staging: tile = 128 rows x 64 B = 8 chunks of 1 KB (16 rows each);
  // wave w stages chunks {2w, 2w+1} of A and of B (4 DMA loads/wave/stage).
  // Chunk lane d: row = ch*16 + (d>>2), u_phys = d&3; fetches global k-unit
  // u_log = u_phys ^ ((row>>2)&3)  (conflict-free b128 reads, R14-verified).
  const int srow = lane >> 2;
  const int sup  = lane & 3;
  unsigned gA[2], gB[2];
#pragma unroll
  for (int c = 0; c < 2; c++) {
    int ch  = w * 2 + c;
    int row = ch * 16 + srow;
    int ul  = sup ^ ((row >> 2) & 3);
    gA[c] = (unsigned)((rowBase + row) * NDIM + ul * 16);
    gB[c] = (unsigned)((colBase + row) * NDIM + ul * 16);
  }

#define STAGE(KT, BUF)                                                    \
  do {                                                                    \
    _Pragma("unroll")                                                     \
    for (int c = 0; c < 2; c++) {                                         \
      int ch = w * 2 + c;                                                 \
      gload_lds16(Xb + gA[c] + (KT) * 64, &As[BUF][ch * 1024]);           \
      gload_lds16(Xb + gB[c] + (KT) * 64, &Bs[BUF][ch * 1024]);           \
    }                                                                     \
  } while (0)

  floatx16 acc[2][2];
#pragma unroll
  for (int a = 0; a < 2; a++)
#pragma unroll
    for (int b = 0; b < 2; b++) acc[a][b] = (floatx16)(0.f);

  STAGE(0, 0);
  STAGE(1, 1);

#pragma unroll
  for (int kt = 0; kt < 8; kt++) {
    const int buf = kt % 3;
    // tile kt landed (own 4 oldest loads retired); kt+1's 4 stay in flight.
    if (kt < 7) asm volatile("s_waitcnt vmcnt(4)" ::: "memory");
    else        asm volatile("s_waitcnt vmcnt(0)" ::: "memory");
    asm volatile("s_barrier" ::: "memory");        // raw: no lgkm drain
    if (kt < 6) STAGE(kt + 2, (kt + 2) % 3);       // distance-2 prefetch

    // fragments: lane holds k = g*32 + [0,32) of its row as 2 x b128
    // (u_log = 2g, 2g+1), un-swizzled via u_phys = u_log ^ ((row>>2)&3)
    intx8 af[2], bf[2];
#pragma unroll
    for (int mt = 0; mt < 2; mt++) {
      const int row = wm * 64 + mt * 32 + m32;
      const int x = (row >> 2) & 3;
      int4 lo = *(const int4*)(&As[buf][row * 64 + ((2 * g)     ^ x) * 16]);
      int4 hi = *(const int4*)(&As[buf][row * 64 + ((2 * g + 1) ^ x) * 16]);
      intx8 f; f[0]=lo.x; f[1]=lo.y; f[2]=lo.z; f[3]=lo.w;
               f[4]=hi.x; f[5]=hi.y; f[6]=hi.z; f[7]=hi.w;
      af[mt] = f;
    }
#pragma unroll
    for (int nt = 0; nt < 2; nt++) {
      const int row = wn * 64 + nt * 32 + m32;
      const int x = (row >> 2) & 3;
      int4 lo = *(const int4*)(&Bs[buf][row * 64 + ((2 * g)     ^ x) * 16]);
      int4 hi = *(const int4*)(&Bs[buf][row * 64 + ((2 * g + 1) ^ x) * 16]);
      intx8 f; f[0]=lo.x; f[1]=lo.y; f[2]=lo.z; f[3]=lo.w;
               f[4]=hi.x; f[5]=hi.y; f[6]=hi.z; f[7]=hi.w;
      bf[nt] = f;
    }
#pragma unroll
    for (int mt = 0; mt < 2; mt++)
#pragma unroll
      for (int nt = 0; nt < 2; nt++)
        acc[mt][nt] = __builtin_amdgcn_mfma_scale_f32_32x32x64_f8f6f4(
            af[mt], bf[nt], acc[mt][nt],
            0 /*A fmt: fp8 e4m3*/, 0 /*B fmt: fp8 e4m3*/,
            0, 127 /*scaleA = 2^0*/, 0, 127 /*scaleB = 2^0*/);
  }

  // Epilogue (R10/R14-verified). 32x32 C/D layout [m74/m101]: col = lane&31,
  // row = (reg&3) + 8*(reg>>2) + 4*(lane>>5), reg in [0,16).
  float lsum = 0.f;
  const bool diag = (bi == bj);
  if (!diag) {
#pragma unroll
    for (int mt = 0; mt < 2; mt++) {
#pragma unroll
      for (int nt = 0; nt < 2; nt++) {
        const int tc = tg[colBase + wn * 64 + nt * 32 + m32];
#pragma unroll
        for (int q = 0; q < 4; q++) {
          const int4 rlv = *(const int4*)(tg + rowBase + wm * 64 + mt * 32 + 4 * g + 8 * q);
          const int rlab[4] = {rlv.x, rlv.y, rlv.z, rlv.w};
#pragma unroll
          for (int j = 0; j < 4; j++) {
            const float s = acc[mt][nt][q * 4 + j];
            lsum += (rlab[j] == tc) ? ((s < 1.f) ? 1.f - s : 0.f)
                                    : ((s > MARGIN) ? s : 0.f);
          }
        }
      }
    }
    lsum *= 2.f;     // pair weight hoisted
  } else {
#pragma unroll
    for (int mt = 0; mt < 2; mt++) {
#pragma unroll
      for (int nt = 0; nt < 2; nt++) {
        const int cloc = wn * 64 + nt * 32 + m32;
        const int tc = tg[colBase + cloc];
        const int col = colBase + cloc;
#pragma unroll
        for (int q = 0; q < 4; q++) {
          const int rbase = wm * 64 + mt * 32 + 4 * g + 8 * q;
          const int4 rlv = *(const int4*)(tg + rowBase + rbase);
          const int rlab[4] = {rlv.x, rlv.y, rlv.z, rlv.w};
#pragma unroll
          for (int j = 0; j < 4; j++) {
            const float s = acc[mt][nt][q * 4 + j];
            float c = (rlab[j] == tc) ? ((s < 1.f) ? 1.f - s : 0.f)
                                      : ((s > MARGIN) ? s : 0.f);
            const int row = rowBase + rbase + j;
            float wgt = (row < col) ? 2.f : ((row == col) ? 1.f : 0.f);
            lsum += wgt * c;
          }
        }
      }
    }
  }

  // block reduce, ONE non-atomic partial store per block
#pragma unroll
  for (int off = 32; off > 0; off >>= 1) lsum += __shfl_down(lsum, off, 64);
  if (lane == 0) red[w] = lsum;
  __syncthreads();
  if (tid == 0) partials[blockIdx.x] = red[0] + red[1] + red[2] + red[3];
}

// 2080 partials -> scalar; one 256-thread block
__global__ void reduce_kernel(const float* __restrict__ partials, float* __restrict__ out) {
  __shared__ float red[4];
  float s = 0.f;
  for (int i = threadIdx.x; i < NT; i += 256) s += partials[i];
#pragma unroll
  for (int off = 32; off > 0; off >>= 1) s += __shfl_down(s, off, 64);
  if ((threadIdx.x & 63) == 0) red[threadIdx.x >> 6] = s;
  __syncthreads();
  if (threadIdx.x == 0)
    out[0] = (red[0] + red[1] + red[2] + red[3]) * (1.0f / NROWS);
}

extern "C" void kernel_launch(void* const* d_in, const int* in_sizes, int n_in,
                              void* d_out, int out_size, void* d_ws, size_t ws_size,
                              hipStream_t stream) {
  const float* x = (const float*)d_in[0];
  const int* tg  = (const int*)d_in[1];
  float* out     = (float*)d_out;
  unsigned char* xb = (unsigned char*)d_ws;                    // fp8 X, 4 MiB
  float* partials   = (float*)((char*)d_ws + (4u << 20));      // 2080 floats

  convert_kernel<<<(NROWS * NDIM / 16) / 256, 256, 0, stream>>>(
      (const float4*)x, (uint4*)xb);
  loss_kernel<<<NT, 256, 0, stream>>>(xb, tg, partials);
  reduce_kernel<<<1, 256, 0, stream>>>(partials, out);
}